// Round 13
// baseline (1988.505 us; speedup 1.0000x reference)
//
#include <hip/hip_runtime.h>
#include <hip/hip_bf16.h>

#define B_   32
#define T_   384
#define CF_  128
#define D_   512
#define H_   16
#define HD_  32
#define L_   16
#define HID_ 512
#define M_   (B_*T_)   // 12288

typedef __bf16 bf16x8 __attribute__((ext_vector_type(8)));
typedef float  f32x4  __attribute__((ext_vector_type(4)));

__device__ __forceinline__ float bf2f(unsigned short u){
    unsigned int x = ((unsigned int)u) << 16;
    return __builtin_bit_cast(float, x);
}
__device__ __forceinline__ unsigned short f2bf(float f){
    unsigned int u = __builtin_bit_cast(unsigned int, f);
    u += 0x7FFFu + ((u >> 16) & 1u);
    return (unsigned short)(u >> 16);
}
__device__ __forceinline__ unsigned int cvtpk(float lo, float hi){
    unsigned int r;
    asm("v_cvt_pk_bf16_f32 %0, %1, %2" : "=v"(r) : "v"(lo), "v"(hi));
    return r;
}

typedef const __attribute__((address_space(1))) unsigned int* gas_p;
typedef __attribute__((address_space(3))) unsigned int*       las_p;
__device__ __forceinline__ void gload16(const void* g, void* l){
    __builtin_amdgcn_global_load_lds((gas_p)g, (las_p)l, 16, 0, 0);
}

// Q pre-scale: 1/sqrt(512) * log2(e), so softmax uses exp2 exactly = e^s
#define QSCALE 0.06376580687097174f

// ---------------------------------------------------------------------------
// Small-GEMM: C[M][N] = A[M][K] * Bt[N][K]^T. 96x128 tile, 4 waves (2x2,
// wave-tile 48x64), BK=32, 2-buffer LDS via global_load_lds (proven R9
// structure). grid (128, N/128) -> 512 blocks = 2/CU exact, 12 MFMA : 7
// ds_read per wave-step.
// EPI: 0=embed(+b+pe+lpe -> bf16 x)  2=residual add bf16 RMW (+bias)
//      3=relu(+bias -> bf16)         4=final (+bias -> f32, ld=128)
// ---------------------------------------------------------------------------
template<int EPI>
__global__ __launch_bounds__(256) void gemm_k(
    const unsigned short* __restrict__ A,
    const unsigned short* __restrict__ Bt,
    const float* __restrict__ aux0,   // bias
    const float* __restrict__ aux1,   // pe
    const float* __restrict__ aux2,   // learnable pe
    float* __restrict__ fout,
    unsigned short* __restrict__ bout,
    int K)
{
    __shared__ unsigned short lA[2][96*32];    // 6 KB each
    __shared__ unsigned short lB[2][128*32];   // 8 KB each

    const int tid  = threadIdx.x;
    const int lane = tid & 63;
    const int w    = tid >> 6;
    const int wm   = w >> 1, wn = w & 1;
    const int li   = lane & 15, ls = lane >> 4;
    const int m0   = blockIdx.x * 96;
    const int n0   = blockIdx.y * 128;
    const int nkt  = K >> 5;

    // A: 384 chunks (tid + [tid<128: tid+256]); B: 512 chunks (2/thread)
    const int ea0 = tid,        ea1 = tid + 256;
    const int ra0 = ea0 >> 2,   sa0 = (ea0 & 3) ^ ((ra0 >> 1) & 3);
    const int ra1 = ea1 >> 2,   sa1 = (ea1 & 3) ^ ((ra1 >> 1) & 3);
    const int eb1 = tid + 256;
    const int rb0 = tid >> 2,   sb0 = (tid & 3) ^ ((rb0 >> 1) & 3);
    const int rb1 = eb1 >> 2,   sb1 = (eb1 & 3) ^ ((rb1 >> 1) & 3);
    const unsigned short* gA0 = A  + (size_t)(m0 + ra0)*K + sa0*8;
    const unsigned short* gA1 = A  + (size_t)(m0 + (ra1 < 96 ? ra1 : 0))*K + sa1*8;
    const unsigned short* gB0 = Bt + (size_t)(n0 + rb0)*K + sb0*8;
    const unsigned short* gB1 = Bt + (size_t)(n0 + rb1)*K + sb1*8;

#define STAGE(c, kt) do{ \
    const int ko_ = (kt)*32; \
    gload16(gA0 + ko_, &lA[c][w*512]); \
    if (tid < 128) gload16(gA1 + ko_, &lA[c][2048 + w*512]); \
    gload16(gB0 + ko_, &lB[c][w*512]); \
    gload16(gB1 + ko_, &lB[c][2048 + w*512]); \
}while(0)

    f32x4 acc[3][4];
    #pragma unroll
    for (int i=0;i<3;i++)
        #pragma unroll
        for (int j=0;j<4;j++) acc[i][j] = (f32x4){0.f,0.f,0.f,0.f};

    STAGE(0, 0);
    asm volatile("s_waitcnt vmcnt(0)" ::: "memory");
    __syncthreads();

    int cur = 0;
    for (int kt = 0; kt < nkt; ++kt){
        if (kt + 1 < nkt) STAGE(cur^1, kt+1);
        bf16x8 af[3], bf[4];
        #pragma unroll
        for (int f=0; f<3; ++f){
            const int rA = wm*48 + f*16 + li;
            af[f] = *(const bf16x8*)&lA[cur][rA*32 + ((ls ^ ((rA>>1)&3))*8)];
        }
        #pragma unroll
        for (int f=0; f<4; ++f){
            const int rB = wn*64 + f*16 + li;
            bf[f] = *(const bf16x8*)&lB[cur][rB*32 + ((ls ^ ((rB>>1)&3))*8)];
        }
        #pragma unroll
        for (int i=0;i<3;i++)
            #pragma unroll
            for (int j=0;j<4;j++)
                acc[i][j] = __builtin_amdgcn_mfma_f32_16x16x32_bf16(af[i], bf[j], acc[i][j], 0, 0, 0);
        __syncthreads();
        cur ^= 1;
    }
#undef STAGE

    // epilogue: D layout col = lane&15, row = (lane>>4)*4 + t  (verified m89)
    #pragma unroll
    for (int i=0;i<3;i++){
        #pragma unroll
        for (int j=0;j<4;j++){
            #pragma unroll
            for (int t=0;t<4;t++){
                const int row = m0 + wm*48 + i*16 + ls*4 + t;
                const int col = n0 + wn*64 + j*16 + li;
                const float v = acc[i][j][t];
                if constexpr (EPI == 0){
                    const int tt = row % T_;
                    bout[row*D_ + col] = f2bf(v + aux0[col] + aux1[tt*D_ + col] + aux2[tt*D_ + col]);
                } else if constexpr (EPI == 2){
                    const int idx = row*D_ + col;
                    bout[idx] = f2bf(bf2f(bout[idx]) + v + aux0[col]);
                } else if constexpr (EPI == 3){
                    const float r = v + aux0[col];
                    bout[row*HID_ + col] = f2bf(r > 0.f ? r : 0.f);
                } else {
                    fout[row*CF_ + col] = v + aux0[col];
                }
            }
        }
    }
}

// ---------------------------------------------------------------------------
// QKV GEMM: 192x192 tile, 4 waves (2x2, wave-tile 96x96), BK=32, 2-buffer
// LDS (48 KB). grid (64,8) = 512 blocks = 2/CU exact. Per wave-step:
// 36 MFMA : 12 ds_read — MFMA-pipe-bound.
// Epilogue: Q scaled by QSCALE -> [bh][t][32]; K -> [bh][t][32];
// V transposed -> [bh][32][T]. (mat boundary straddle handled per-element.)
// ---------------------------------------------------------------------------
__global__ __launch_bounds__(256) void gemm192_k(
    const unsigned short* __restrict__ A,
    const unsigned short* __restrict__ Bt,
    unsigned short* __restrict__ bout,
    int K)
{
    __shared__ unsigned short lA[2][192*32];     // 12 KB each
    __shared__ unsigned short lB[2][192*32];     // 12 KB each

    const int tid  = threadIdx.x;
    const int lane = tid & 63;
    const int w    = tid >> 6;
    const int wm   = w >> 1, wn = w & 1;
    const int li   = lane & 15, ls = lane >> 4;
    const int m0   = blockIdx.x * 192;
    const int n0   = blockIdx.y * 192;
    const int nkt  = K >> 5;

    // A and B: 768 chunks each, 3/thread
    const int e0 = tid, e1 = tid + 256, e2 = tid + 512;
    const int r0 = e0 >> 2, s0 = (e0 & 3) ^ ((r0 >> 1) & 3);
    const int r1 = e1 >> 2, s1 = (e1 & 3) ^ ((r1 >> 1) & 3);
    const int r2 = e2 >> 2, s2 = (e2 & 3) ^ ((r2 >> 1) & 3);
    const unsigned short* gA0 = A + (size_t)(m0 + r0)*K + s0*8;
    const unsigned short* gA1 = A + (size_t)(m0 + r1)*K + s1*8;
    const unsigned short* gA2 = A + (size_t)(m0 + r2)*K + s2*8;
    const unsigned short* gB0 = Bt + (size_t)(n0 + r0)*K + s0*8;
    const unsigned short* gB1 = Bt + (size_t)(n0 + r1)*K + s1*8;
    const unsigned short* gB2 = Bt + (size_t)(n0 + r2)*K + s2*8;

#define STAGE192(c, kt) do{ \
    const int ko_ = (kt)*32; \
    gload16(gA0 + ko_, &lA[c][w*512]); \
    gload16(gA1 + ko_, &lA[c][2048 + w*512]); \
    gload16(gA2 + ko_, &lA[c][4096 + w*512]); \
    gload16(gB0 + ko_, &lB[c][w*512]); \
    gload16(gB1 + ko_, &lB[c][2048 + w*512]); \
    gload16(gB2 + ko_, &lB[c][4096 + w*512]); \
}while(0)

    f32x4 acc[6][6];
    #pragma unroll
    for (int i=0;i<6;i++)
        #pragma unroll
        for (int j=0;j<6;j++) acc[i][j] = (f32x4){0.f,0.f,0.f,0.f};

    STAGE192(0, 0);
    asm volatile("s_waitcnt vmcnt(0)" ::: "memory");
    __syncthreads();

    int cur = 0;
    for (int kt = 0; kt < nkt; ++kt){
        if (kt + 1 < nkt) STAGE192(cur^1, kt+1);
        bf16x8 af[6], bf[6];
        #pragma unroll
        for (int f=0; f<6; ++f){
            const int rA = wm*96 + f*16 + li;
            af[f] = *(const bf16x8*)&lA[cur][rA*32 + ((ls ^ ((rA>>1)&3))*8)];
            const int rB = wn*96 + f*16 + li;
            bf[f] = *(const bf16x8*)&lB[cur][rB*32 + ((ls ^ ((rB>>1)&3))*8)];
        }
        #pragma unroll
        for (int i=0;i<6;i++)
            #pragma unroll
            for (int j=0;j<6;j++)
                acc[i][j] = __builtin_amdgcn_mfma_f32_16x16x32_bf16(af[i], bf[j], acc[i][j], 0, 0, 0);
        __syncthreads();
        cur ^= 1;
    }
#undef STAGE192

    // QKV scatter epilogue
    #pragma unroll
    for (int i=0;i<6;i++){
        #pragma unroll
        for (int j=0;j<6;j++){
            const int row0 = m0 + wm*96 + i*16 + ls*4;
            const int col  = n0 + wn*96 + j*16 + li;
            const int mat = col >> 9, nl = col & 511;
            const int hh = nl >> 5, dd = nl & 31;
            const int bb = row0 / T_, tt0 = row0 - bb*T_;
            if (mat == 2){
                alignas(8) unsigned short p4[4];
                #pragma unroll
                for (int t=0;t<4;t++) p4[t] = f2bf(acc[i][j][t]);
                *(uint2*)(bout + 2*(size_t)(M_*D_)
                          + ((size_t)(bb*H_ + hh)*HD_ + dd)*T_ + tt0) = *(const uint2*)p4;
            } else {
                #pragma unroll
                for (int t=0;t<4;t++){
                    float v = acc[i][j][t];
                    if (mat == 0) v *= QSCALE;
                    bout[(size_t)mat*(M_*D_)
                         + (((size_t)(bb*H_ + hh)*T_ + tt0 + t)*HD_) + dd] = f2bf(v);
                }
            }
        }
    }
}

// ---------------------------------------------------------------------------
// LayerNorm: one wave per row of 512, bf16 in -> bf16 out
// ---------------------------------------------------------------------------
__global__ __launch_bounds__(256) void ln_k(const unsigned short* __restrict__ x,
                                            const float* __restrict__ g,
                                            const float* __restrict__ b,
                                            unsigned short* __restrict__ out)
{
    const int w = threadIdx.x >> 6, lane = threadIdx.x & 63;
    const int row = blockIdx.x*4 + w;
    const unsigned short* xr = x + (size_t)row*D_ + lane*8;
    const uint4 raw = *(const uint4*)xr;
    const unsigned short* rs = (const unsigned short*)&raw;
    float v8[8];
    float s = 0.f, q2 = 0.f;
    #pragma unroll
    for (int i=0;i<8;i++){
        v8[i] = bf2f(rs[i]);
        s  += v8[i];
        q2 += v8[i]*v8[i];
    }
    #pragma unroll
    for (int off=32; off; off>>=1){
        s  += __shfl_xor(s,  off);
        q2 += __shfl_xor(q2, off);
    }
    const float mean = s * (1.f/512.f);
    const float var  = q2 * (1.f/512.f) - mean*mean;
    const float rstd = rsqrtf(var + 1e-6f);
    const float4 gA = *(const float4*)(g + lane*8);
    const float4 gB = *(const float4*)(g + lane*8 + 4);
    const float4 bA = *(const float4*)(b + lane*8);
    const float4 bB = *(const float4*)(b + lane*8 + 4);
    alignas(16) unsigned short o8[8];
    o8[0] = f2bf((v8[0]-mean)*rstd*gA.x + bA.x);
    o8[1] = f2bf((v8[1]-mean)*rstd*gA.y + bA.y);
    o8[2] = f2bf((v8[2]-mean)*rstd*gA.z + bA.z);
    o8[3] = f2bf((v8[3]-mean)*rstd*gA.w + bA.w);
    o8[4] = f2bf((v8[4]-mean)*rstd*gB.x + bB.x);
    o8[5] = f2bf((v8[5]-mean)*rstd*gB.y + bB.y);
    o8[6] = f2bf((v8[6]-mean)*rstd*gB.z + bB.z);
    o8[7] = f2bf((v8[7]-mean)*rstd*gB.w + bB.w);
    *(uint4*)(out + (size_t)row*D_ + lane*8) = *(const uint4*)o8;
}

// ---------------------------------------------------------------------------
// Causal flash attention (R6/R9 proven version). q,k: [bh][T][32] bf16
// (Q pre-scaled by QSCALE), vt: [bh][32][T] bf16. Fixed m=0 softmax, exp2.
// 128 q-rows/block, 32 q-rows/wave via two Q-frags; static named 1-deep
// prefetch regs (rule #20). Boundary chunk peeled. No __syncthreads.
// Grid 1536 x 256 threads, XCD-chunk swizzled.
// ---------------------------------------------------------------------------
__global__ __launch_bounds__(256) void attn_k(const unsigned short* __restrict__ q,
                                              const unsigned short* __restrict__ k,
                                              const unsigned short* __restrict__ vt,
                                              unsigned short* __restrict__ o)
{
    __shared__ unsigned int Pb[4][2*16*18];      // per-wave: A frag @0, B frag @288 (dwords)

    // bijective XCD-chunk swizzle: 1536 = 8 XCDs * 192
    const int orig = blockIdx.x;
    const int wg   = (orig & 7)*192 + (orig >> 3);
    const int bh   = wg / 3;
    const int t0   = (wg - bh*3) * 128;

    const int tid  = threadIdx.x;
    const int lane = tid & 63, w = tid >> 6;
    const int li   = lane & 15, ls = lane >> 4;
    const unsigned short* qb = q  + (size_t)bh*(T_*HD_);
    const unsigned short* kb = k  + (size_t)bh*(T_*HD_);
    const unsigned short* vb = vt + (size_t)bh*(HD_*T_);   // [32][384]

    const int trow0 = t0 + w*32;                 // wave's 32 q-rows
    const bf16x8 qaA = *(const bf16x8*)(qb + (trow0 + li)*HD_ + ls*8);
    const bf16x8 qaB = *(const bf16x8*)(qb + (trow0 + 16 + li)*HD_ + ls*8);
    const int nfull = trow0 >> 5;                // full (unmasked) 32-k chunks

    float lsA = 0.f, lsB = 0.f;
    f32x4 oA0={0.f,0.f,0.f,0.f}, oA1={0.f,0.f,0.f,0.f};
    f32x4 oB0={0.f,0.f,0.f,0.f}, oB1={0.f,0.f,0.f,0.f};
    unsigned int* pwA = Pb[w];
    unsigned int* pwB = Pb[w] + 288;

    bf16x8 kf0 = *(const bf16x8*)(kb + li*HD_ + ls*8);
    bf16x8 kf1 = *(const bf16x8*)(kb + (16 + li)*HD_ + ls*8);
    bf16x8 vf0 = *(const bf16x8*)(vb + li*T_ + ls*8);
    bf16x8 vf1 = *(const bf16x8*)(vb + (16 + li)*T_ + ls*8);

    for (int c = 0; c < nfull; ++c){
        f32x4 sA0={0.f,0.f,0.f,0.f}, sA1={0.f,0.f,0.f,0.f};
        f32x4 sB0={0.f,0.f,0.f,0.f}, sB1={0.f,0.f,0.f,0.f};
        sA0 = __builtin_amdgcn_mfma_f32_16x16x32_bf16(kf0, qaA, sA0, 0, 0, 0);
        sA1 = __builtin_amdgcn_mfma_f32_16x16x32_bf16(kf1, qaA, sA1, 0, 0, 0);
        sB0 = __builtin_amdgcn_mfma_f32_16x16x32_bf16(kf0, qaB, sB0, 0, 0, 0);
        sB1 = __builtin_amdgcn_mfma_f32_16x16x32_bf16(kf1, qaB, sB1, 0, 0, 0);
        kf0 = *(const bf16x8*)(kb + ((c+1)*32 + li)*HD_ + ls*8);
        kf1 = *(const bf16x8*)(kb + ((c+1)*32 + 16 + li)*HD_ + ls*8);

        float pA0[4], pA1[4], pB0[4], pB1[4];
        #pragma unroll
        for (int j=0;j<4;j++){
            pA0[j] = exp2f(sA0[j]); pA1[j] = exp2f(sA1[j]);
            pB0[j] = exp2f(sB0[j]); pB1[j] = exp2f(sB1[j]);
        }
        lsA += pA0[0]+pA0[1]+pA0[2]+pA0[3]+pA1[0]+pA1[1]+pA1[2]+pA1[3];
        lsB += pB0[0]+pB0[1]+pB0[2]+pB0[3]+pB1[0]+pB1[1]+pB1[2]+pB1[3];

        const uint2 wA0 = { cvtpk(pA0[0], pA0[1]), cvtpk(pA0[2], pA0[3]) };
        const uint2 wA1 = { cvtpk(pA1[0], pA1[1]), cvtpk(pA1[2], pA1[3]) };
        const uint2 wB0 = { cvtpk(pB0[0], pB0[1]), cvtpk(pB0[2], pB0[3]) };
        const uint2 wB1 = { cvtpk(pB1[0], pB1[1]), cvtpk(pB1[2], pB1[3]) };
        *(uint2*)&pwA[li*18 + ls*2]     = wA0;
        *(uint2*)&pwA[li*18 + 8 + ls*2] = wA1;
        *(uint2*)&pwB[li*18 + ls*2]     = wB0;
        *(uint2*)&pwB[li*18 + 8 + ls*2] = wB1;
        asm volatile("s_waitcnt lgkmcnt(0)" ::: "memory");
        const bf16x8 paA = *(const bf16x8*)&pwA[li*18 + ls*4];
        const bf16x8 paB = *(const bf16x8*)&pwB[li*18 + ls*4];

        oA0 = __builtin_amdgcn_mfma_f32_16x16x32_bf16(paA, vf0, oA0, 0, 0, 0);
        oA1 = __builtin_amdgcn_mfma_f32_16x16x32_bf16(paA, vf1, oA1, 0, 0, 0);
        oB0 = __builtin_amdgcn_mfma_f32_16x16x32_bf16(paB, vf0, oB0, 0, 0, 0);
        oB1 = __builtin_amdgcn_mfma_f32_16x16x32_bf16(paB, vf1, oB1, 0, 0, 0);
        vf0 = *(const bf16x8*)(vb + li*T_ + (c+1)*32 + ls*8);
        vf1 = *(const bf16x8*)(vb + (16 + li)*T_ + (c+1)*32 + ls*8);
    }

    // ---- boundary chunk c = nfull (k base = trow0), causal-masked ----
    {
        f32x4 sA0={0.f,0.f,0.f,0.f}, sB0={0.f,0.f,0.f,0.f}, sB1={0.f,0.f,0.f,0.f};
        sA0 = __builtin_amdgcn_mfma_f32_16x16x32_bf16(kf0, qaA, sA0, 0, 0, 0);
        sB0 = __builtin_amdgcn_mfma_f32_16x16x32_bf16(kf0, qaB, sB0, 0, 0, 0);
        sB1 = __builtin_amdgcn_mfma_f32_16x16x32_bf16(kf1, qaB, sB1, 0, 0, 0);

        const int qA = li, qB = 16 + li;
        float pA0[4], pB0[4], pB1[4];
        #pragma unroll
        for (int j=0;j<4;j++){
            const int k0 = ls*4 + j;
            pA0[j] = (k0 <= qA)      ? exp2f(sA0[j]) : 0.f;
            pB0[j] = exp2f(sB0[j]);
            pB1[j] = (k0 + 16 <= qB) ? exp2f(sB1[j]) : 0.f;
        }
        lsA += pA0[0]+pA0[1]+pA0[2]+pA0[3];
        lsB += pB0[0]+pB0[1]+pB0[2]+pB0[3]+pB1[0]+pB1[1]+pB1[2]+pB1[3];

        const uint2 wA0 = { cvtpk(pA0[0], pA0[1]), cvtpk(pA0[2], pA0[3]) };
        const uint2 wB0 = { cvtpk(pB0[0], pB0[1]), cvtpk(pB0[2], pB0[3]) };
        const uint2 wB1 = { cvtpk(pB1[0], pB1[1]), cvtpk(pB1[2], pB1[3]) };
        const uint2 zz  = { 0u, 0u };
        *(uint2*)&pwA[li*18 + ls*2]     = wA0;
        *(uint2*)&pwA[li*18 + 8 + ls*2] = zz;
        *(uint2*)&pwB[li*18 + ls*2]     = wB0;
        *(uint2*)&pwB[li*18 + 8 + ls*2] = wB1;
        asm volatile("s_waitcnt lgkmcnt(0)" ::: "memory");
        const bf16x8 paA = *(const bf16x8*)&pwA[li*18 + ls*4];
        const bf16x8 paB = *(const bf16x8*)&pwB[li*18 + ls*4];

        oA0 = __builtin_amdgcn_mfma_f32_16x16x32_bf16(paA, vf0, oA0, 0, 0, 0);
        oA1 = __builtin_amdgcn_mfma_f32_16x16x32_bf16(paA, vf1, oA1, 0, 0, 0);
        oB0 = __builtin_amdgcn_mfma_f32_16x16x32_bf16(paB, vf0, oB0, 0, 0, 0);
        oB1 = __builtin_amdgcn_mfma_f32_16x16x32_bf16(paB, vf1, oB1, 0, 0, 0);
    }

    lsA += __shfl_xor(lsA, 16);  lsA += __shfl_xor(lsA, 32);
    lsB += __shfl_xor(lsB, 16);  lsB += __shfl_xor(lsB, 32);

    const int bb = bh >> 4, hh = bh & 15;
    #pragma unroll
    for (int j=0;j<4;j++){
        const float rsA = __shfl(lsA, ls*4 + j);
        const float rsB = __shfl(lsB, ls*4 + j);
        const float iA = 1.f / rsA, iB = 1.f / rsB;
        const int tgA = trow0 + ls*4 + j;
        const int tgB = tgA + 16;
        o[(size_t)(bb*T_ + tgA)*D_ + hh*HD_ + li]      = f2bf(oA0[j]*iA);
        o[(size_t)(bb*T_ + tgA)*D_ + hh*HD_ + 16 + li] = f2bf(oA1[j]*iA);
        o[(size_t)(bb*T_ + tgB)*D_ + hh*HD_ + li]      = f2bf(oB0[j]*iB);
        o[(size_t)(bb*T_ + tgB)*D_ + hh*HD_ + 16 + li] = f2bf(oB1[j]*iB);
    }
}

// ---------------------------------------------------------------------------
// Coalesced tiled transpose packs (f32 -> bf16)
// ---------------------------------------------------------------------------
__global__ __launch_bounds__(256) void packT_k(const float* __restrict__ src,
                                               unsigned short* __restrict__ dst,
                                               int R, int C)
{
    __shared__ unsigned short tile[64][72];
    const int z  = blockIdx.z;
    const float* s = src + (size_t)z*R*C;
    unsigned short* d = dst + (size_t)z*R*C;
    const int c0 = blockIdx.x*64, r0 = blockIdx.y*64;

    for (int it = threadIdx.x; it < 1024; it += 256){
        const int rr  = it >> 4;
        const int cc4 = (it & 15) << 2;
        const float4 v = *(const float4*)(s + (size_t)(r0+rr)*C + c0 + cc4);
        tile[cc4  ][rr] = f2bf(v.x);
        tile[cc4+1][rr] = f2bf(v.y);
        tile[cc4+2][rr] = f2bf(v.z);
        tile[cc4+3][rr] = f2bf(v.w);
    }
    __syncthreads();
    for (int it = threadIdx.x; it < 512; it += 256){
        const int cc = it >> 3;
        const int ch = (it & 7) << 3;
        *(uint4*)(d + (size_t)(c0+cc)*R + r0 + ch) = *(const uint4*)&tile[cc][ch];
    }
}

__global__ __launch_bounds__(256) void pack_qkv_k(const float* __restrict__ Wq,
                                                  const float* __restrict__ Wk,
                                                  const float* __restrict__ Wv,
                                                  unsigned short* __restrict__ dst)
{
    __shared__ unsigned short tile[32][136];
    const int kc  = blockIdx.x;
    const int mat = blockIdx.y >> 4;
    const int h   = blockIdx.y & 15;
    const int l   = blockIdx.z;
    const float* src = ((mat==0) ? Wq : (mat==1) ? Wk : Wv)
                     + ((size_t)(l*H_ + h)*D_ + kc*128)*HD_;

    for (int it = threadIdx.x; it < 1024; it += 256){
        const int rr  = it >> 3;
        const int dd4 = (it & 7) << 2;
        const float4 v = *(const float4*)(src + (size_t)rr*HD_ + dd4);
        tile[dd4  ][rr] = f2bf(v.x);
        tile[dd4+1][rr] = f2bf(v.y);
        tile[dd4+2][rr] = f2bf(v.z);
        tile[dd4+3][rr] = f2bf(v.w);
    }
    __syncthreads();
    unsigned short* dp = dst + (size_t)l*786432 + (size_t)mat*262144 + kc*128;
    for (int it = threadIdx.x; it < 512; it += 256){
        const int dd = it >> 4;
        const int ch = (it & 15) << 3;
        *(uint4*)(dp + (size_t)(h*32 + dd)*512 + ch) = *(const uint4*)&tile[dd][ch];
    }
}

__global__ void cast4_k(const float* __restrict__ src, unsigned short* __restrict__ dst, int total4)
{
    const int i = blockIdx.x*256 + threadIdx.x;
    if (i >= total4) return;
    const float4 vv = ((const float4*)src)[i];
    alignas(8) unsigned short t[4] = { f2bf(vv.x), f2bf(vv.y), f2bf(vv.z), f2bf(vv.w) };
    *(uint2*)(dst + (size_t)i*4) = *(const uint2*)t;
}

__global__ __launch_bounds__(256) void loss1_k(const float* __restrict__ logits,
                                               const float* __restrict__ tgt,
                                               float* __restrict__ part)
{
    float s = 0.f;
    for (int i = blockIdx.x*256 + threadIdx.x; i < M_*CF_; i += 256*1024){
        const float d = logits[i] - tgt[i];
        s += d*d;
    }
    #pragma unroll
    for (int off=32; off; off>>=1) s += __shfl_xor(s, off);
    __shared__ float ws4[4];
    if ((threadIdx.x & 63) == 0) ws4[threadIdx.x >> 6] = s;
    __syncthreads();
    if (threadIdx.x == 0) part[blockIdx.x] = ws4[0]+ws4[1]+ws4[2]+ws4[3];
}

__global__ __launch_bounds__(256) void loss2_k(const float* __restrict__ part,
                                               float* __restrict__ out)
{
    float s = 0.f;
    for (int i = threadIdx.x; i < 1024; i += 256) s += part[i];
    #pragma unroll
    for (int off=32; off; off>>=1) s += __shfl_xor(s, off);
    __shared__ float ws4[4];
    if ((threadIdx.x & 63) == 0) ws4[threadIdx.x >> 6] = s;
    __syncthreads();
    if (threadIdx.x == 0) out[0] = (ws4[0]+ws4[1]+ws4[2]+ws4[3]) * (1.f/(float)(M_*CF_));
}

// ---------------------------------------------------------------------------
// Host
// ---------------------------------------------------------------------------
static constexpr size_t X_OFF     = 0;            // bf16 x       12,582,912 B (region reserved 25 MB)
static constexpr size_t H_OFF     = 25165824;     // bf16 h/xb    12,582,912 B
static constexpr size_t O_OFF     = 37748736;     // bf16 o/u/idx 12,582,912 B
static constexpr size_t QKV_OFF   = 50331648;     // bf16 q,k,vt  37,748,736 B
static constexpr size_t WQKV_OFF  = 88080384;     // bf16         25,165,824 B
static constexpr size_t WPROJ_OFF = 113246208;    // bf16          8,388,608 B
static constexpr size_t W1_OFF    = 121634816;    // bf16          8,388,608 B
static constexpr size_t W2_OFF    = 130023424;    // bf16          8,388,608 B
static constexpr size_t WEMB_OFF  = 138412032;    // bf16            131,072 B
static constexpr size_t WFIN_OFF  = 138543104;    // bf16            131,072 B
static constexpr size_t PART_OFF  = 138674176;    // f32               4,096 B

extern "C" void kernel_launch(void* const* d_in, const int* in_sizes, int n_in,
                              void* d_out, int out_size, void* d_ws, size_t ws_size,
                              hipStream_t stream)
{
    const float* index   = (const float*)d_in[0];
    const float* targets = (const float*)d_in[1];
    const float* W_embed = (const float*)d_in[2];
    const float* b_embed = (const float*)d_in[3];
    const float* pe      = (const float*)d_in[4];
    const float* lpe     = (const float*)d_in[5];
    const float* Wq      = (const float*)d_in[6];
    const float* Wk      = (const float*)d_in[7];
    const float* Wv      = (const float*)d_in[8];
    const float* Wproj   = (const float*)d_in[9];
    const float* bproj   = (const float*)d_in[10];
    const float* ln1g    = (const float*)d_in[11];
    const float* ln1b    = (const float*)d_in[12];
    const float* ln2g    = (const float*)d_in[13];
    const float* ln2b    = (const float*)d_in[14];
    const float* W1      = (const float*)d_in[15];
    const float* b1      = (const float*)d_in[16];
    const float* W2      = (const float*)d_in[17];
    const float* b2      = (const float*)d_in[18];
    const float* Wfin    = (const float*)d_in[19];
    const float* bfin    = (const float*)d_in[20];

    char* ws = (char*)d_ws;
    unsigned short* xb    = (unsigned short*)(ws + X_OFF);
    unsigned short* hbuf  = (unsigned short*)(ws + H_OFF);
    unsigned short* obuf  = (unsigned short*)(ws + O_OFF);
    unsigned short* qkv   = (unsigned short*)(ws + QKV_OFF);
    unsigned short* wqkvp = (unsigned short*)(ws + WQKV_OFF);
    unsigned short* wprojp= (unsigned short*)(ws + WPROJ_OFF);
    unsigned short* w1p   = (unsigned short*)(ws + W1_OFF);
    unsigned short* w2p   = (unsigned short*)(ws + W2_OFF);
    unsigned short* wembp = (unsigned short*)(ws + WEMB_OFF);
    unsigned short* wfinp = (unsigned short*)(ws + WFIN_OFF);
    float*          part  = (float*)(ws + PART_OFF);
    float*          logits= (float*)d_out;

    // pack weights to bf16 B^T layouts (coalesced LDS-transpose)
    pack_qkv_k<<<dim3(4,48,16), 256, 0, stream>>>(Wq, Wk, Wv, wqkvp);
    packT_k<<<dim3(8,8,16), 256, 0, stream>>>(Wproj, wprojp, 512, 512);
    packT_k<<<dim3(8,8,16), 256, 0, stream>>>(W1,    w1p,    512, 512);
    packT_k<<<dim3(8,8,16), 256, 0, stream>>>(W2,    w2p,    512, 512);
    packT_k<<<dim3(8,2,1),  256, 0, stream>>>(W_embed, wembp, 128, 512);
    packT_k<<<dim3(2,8,1),  256, 0, stream>>>(Wfin,    wfinp, 512, 128);

    // embed: x = bf16(index) @ Wemb^T + b + pe + lpe   (x in bf16)
    cast4_k<<<1536, 256, 0, stream>>>(index, obuf, 393216);
    gemm_k<0><<<dim3(128,4), 256, 0, stream>>>(obuf, wembp, b_embed, pe, lpe, nullptr, xb, 128);

    for (int l = 0; l < L_; ++l){
        ln_k<<<3072, 256, 0, stream>>>(xb, ln1g + l*512, ln1b + l*512, hbuf);
        gemm192_k<<<dim3(64,8), 256, 0, stream>>>(hbuf, wqkvp + (size_t)l*786432, qkv, 512);
        attn_k<<<1536, 256, 0, stream>>>(qkv, qkv + 6291456, qkv + 2*6291456, obuf);
        gemm_k<2><<<dim3(128,4), 256, 0, stream>>>(obuf, wprojp + (size_t)l*262144,
                                                   bproj + l*512, nullptr, nullptr, nullptr, xb, 512);
        ln_k<<<3072, 256, 0, stream>>>(xb, ln2g + l*512, ln2b + l*512, hbuf);
        gemm_k<3><<<dim3(128,4), 256, 0, stream>>>(hbuf, w1p + (size_t)l*262144,
                                                   b1 + l*512, nullptr, nullptr, nullptr, obuf, 512);
        gemm_k<2><<<dim3(128,4), 256, 0, stream>>>(obuf, w2p + (size_t)l*262144,
                                                   b2 + l*512, nullptr, nullptr, nullptr, xb, 512);
    }

    // final: logits = x @ Wfin^T + b_final ; loss = mean((logits-targets)^2)
    gemm_k<4><<<dim3(128,1), 256, 0, stream>>>(xb, wfinp, bfin, nullptr, nullptr, logits, nullptr, 512);
    loss1_k<<<1024, 256, 0, stream>>>(logits, targets, part);
    loss2_k<<<1, 256, 0, stream>>>(part, logits + 1572864);
}

// Round 14
// 1851.089 us; speedup vs baseline: 1.0742x; 1.0742x over previous
//
#include <hip/hip_runtime.h>
#include <hip/hip_bf16.h>

#define B_   32
#define T_   384
#define CF_  128
#define D_   512
#define H_   16
#define HD_  32
#define L_   16
#define HID_ 512
#define M_   (B_*T_)   // 12288

typedef __bf16 bf16x8 __attribute__((ext_vector_type(8)));
typedef float  f32x4  __attribute__((ext_vector_type(4)));

__device__ __forceinline__ float bf2f(unsigned short u){
    unsigned int x = ((unsigned int)u) << 16;
    return __builtin_bit_cast(float, x);
}
__device__ __forceinline__ unsigned short f2bf(float f){
    unsigned int u = __builtin_bit_cast(unsigned int, f);
    u += 0x7FFFu + ((u >> 16) & 1u);
    return (unsigned short)(u >> 16);
}
__device__ __forceinline__ unsigned int cvtpk(float lo, float hi){
    unsigned int r;
    asm("v_cvt_pk_bf16_f32 %0, %1, %2" : "=v"(r) : "v"(lo), "v"(hi));
    return r;
}

typedef const __attribute__((address_space(1))) unsigned int* gas_p;
typedef __attribute__((address_space(3))) unsigned int*       las_p;
__device__ __forceinline__ void gload16(const void* g, void* l){
    __builtin_amdgcn_global_load_lds((gas_p)g, (las_p)l, 16, 0, 0);
}

// Q pre-scale: 1/sqrt(512) * log2(e), so softmax uses exp2 exactly = e^s
#define QSCALE 0.06376580687097174f

// ---------------------------------------------------------------------------
// Small-GEMM (R12-proven): C[M][N] = A[M][K] * Bt[N][K]^T. 64x128 tile,
// 4 waves (2x2, wave-tile 32x64), BK=32, 2-buffer LDS via global_load_lds.
// grid (192, N/128) -> 768 blocks = 3/CU exact.
// EPI: 0=embed(+b+pe+lpe -> bf16 x)  2=residual add bf16 RMW (+bias)
//      3=relu(+bias -> bf16)
//      4=final (+bias -> f32, ld=128) + fused MSE partial (part[block])
// ---------------------------------------------------------------------------
template<int EPI>
__global__ __launch_bounds__(256) void gemm_k(
    const unsigned short* __restrict__ A,
    const unsigned short* __restrict__ Bt,
    const float* __restrict__ aux0,   // bias
    const float* __restrict__ aux1,   // pe  (EPI4: targets)
    const float* __restrict__ aux2,   // learnable pe
    float* __restrict__ fout,
    unsigned short* __restrict__ bout,
    float* __restrict__ part,         // EPI4: per-block SSE partial
    int K)
{
    __shared__ unsigned short lA[2][64*32];    // 4 KB each
    __shared__ unsigned short lB[2][128*32];   // 8 KB each
    __shared__ float red4[4];

    const int tid  = threadIdx.x;
    const int lane = tid & 63;
    const int w    = tid >> 6;
    const int wm   = w >> 1, wn = w & 1;
    const int li   = lane & 15, ls = lane >> 4;
    const int m0   = blockIdx.x * 64;
    const int n0   = blockIdx.y * 128;
    const int nkt  = K >> 5;

    // A: 256 chunks (1/thread); B: 512 chunks (2/thread)
    const int ra0 = tid >> 2,          sa0 = (tid & 3) ^ ((ra0 >> 1) & 3);
    const int eb1 = tid + 256;
    const int rb0 = tid >> 2,          sb0 = (tid & 3) ^ ((rb0 >> 1) & 3);
    const int rb1 = eb1 >> 2,          sb1 = (eb1 & 3) ^ ((rb1 >> 1) & 3);
    const unsigned short* gA0 = A  + (size_t)(m0 + ra0)*K + sa0*8;
    const unsigned short* gB0 = Bt + (size_t)(n0 + rb0)*K + sb0*8;
    const unsigned short* gB1 = Bt + (size_t)(n0 + rb1)*K + sb1*8;

#define STAGE(c, kt) do{ \
    const int ko_ = (kt)*32; \
    gload16(gA0 + ko_, &lA[c][w*512]); \
    gload16(gB0 + ko_, &lB[c][w*512]); \
    gload16(gB1 + ko_, &lB[c][2048 + w*512]); \
}while(0)

    f32x4 acc[2][4];
    #pragma unroll
    for (int i=0;i<2;i++)
        #pragma unroll
        for (int j=0;j<4;j++) acc[i][j] = (f32x4){0.f,0.f,0.f,0.f};

    STAGE(0, 0);
    asm volatile("s_waitcnt vmcnt(0)" ::: "memory");
    __syncthreads();

    int cur = 0;
    for (int kt = 0; kt < nkt; ++kt){
        if (kt + 1 < nkt) STAGE(cur^1, kt+1);
        bf16x8 af[2], bf[4];
        #pragma unroll
        for (int f=0; f<2; ++f){
            const int rA = wm*32 + f*16 + li;
            af[f] = *(const bf16x8*)&lA[cur][rA*32 + ((ls ^ ((rA>>1)&3))*8)];
        }
        #pragma unroll
        for (int f=0; f<4; ++f){
            const int rB = wn*64 + f*16 + li;
            bf[f] = *(const bf16x8*)&lB[cur][rB*32 + ((ls ^ ((rB>>1)&3))*8)];
        }
        #pragma unroll
        for (int i=0;i<2;i++)
            #pragma unroll
            for (int j=0;j<4;j++)
                acc[i][j] = __builtin_amdgcn_mfma_f32_16x16x32_bf16(af[i], bf[j], acc[i][j], 0, 0, 0);
        __syncthreads();
        cur ^= 1;
    }
#undef STAGE

    // epilogue: D layout col = lane&15, row = (lane>>4)*4 + t  (verified m89)
    float sse = 0.f;
    #pragma unroll
    for (int i=0;i<2;i++){
        #pragma unroll
        for (int j=0;j<4;j++){
            #pragma unroll
            for (int t=0;t<4;t++){
                const int row = m0 + wm*32 + i*16 + ls*4 + t;
                const int col = n0 + wn*64 + j*16 + li;
                const float v = acc[i][j][t];
                if constexpr (EPI == 0){
                    const int tt = row % T_;
                    bout[row*D_ + col] = f2bf(v + aux0[col] + aux1[tt*D_ + col] + aux2[tt*D_ + col]);
                } else if constexpr (EPI == 2){
                    const int idx = row*D_ + col;
                    bout[idx] = f2bf(bf2f(bout[idx]) + v + aux0[col]);
                } else if constexpr (EPI == 3){
                    const float r = v + aux0[col];
                    bout[row*HID_ + col] = f2bf(r > 0.f ? r : 0.f);
                } else {
                    const float lv = v + aux0[col];
                    fout[row*CF_ + col] = lv;
                    const float d = lv - aux1[row*CF_ + col];
                    sse += d*d;
                }
            }
        }
    }
    if constexpr (EPI == 4){
        #pragma unroll
        for (int off=32; off; off>>=1) sse += __shfl_xor(sse, off);
        if (lane == 0) red4[w] = sse;
        __syncthreads();
        if (tid == 0) part[blockIdx.x] = red4[0]+red4[1]+red4[2]+red4[3];
    }
}

// ---------------------------------------------------------------------------
// QKV GEMM (R9/R12-proven): 128x192 tile, 4 waves (2x2, wave-tile 64x96),
// BK=32, 2-buffer LDS. grid (96,8) = 768 blocks = 3/CU exact.
// Epilogue: Q scaled by QSCALE -> [bh][t][32]; K -> [bh][t][32];
// V transposed -> [bh][32][T].
// ---------------------------------------------------------------------------
__global__ __launch_bounds__(256) void gemm192_k(
    const unsigned short* __restrict__ A,
    const unsigned short* __restrict__ Bt,
    unsigned short* __restrict__ bout,
    int K)
{
    __shared__ unsigned short lA[2][128*32];     // 8 KB each
    __shared__ unsigned short lB[2][192*32];     // 12 KB each

    const int tid  = threadIdx.x;
    const int lane = tid & 63;
    const int w    = tid >> 6;
    const int wm   = w >> 1, wn = w & 1;
    const int li   = lane & 15, ls = lane >> 4;
    const int m0   = blockIdx.x * 128;
    const int n0   = blockIdx.y * 192;
    const int nkt  = K >> 5;

    const int ea0 = tid, ea1 = tid + 256;
    const int ra0 = ea0 >> 2, sa0 = (ea0 & 3) ^ ((ra0 >> 1) & 3);
    const int ra1 = ea1 >> 2, sa1 = (ea1 & 3) ^ ((ra1 >> 1) & 3);
    const unsigned short* gA0 = A + (size_t)(m0 + ra0)*K + sa0*8;
    const unsigned short* gA1 = A + (size_t)(m0 + ra1)*K + sa1*8;

    const int eb0 = tid, eb1 = tid + 256, eb2 = tid + 512;
    const int rb0 = eb0 >> 2, sb0 = (eb0 & 3) ^ ((rb0 >> 1) & 3);
    const int rb1 = eb1 >> 2, sb1 = (eb1 & 3) ^ ((rb1 >> 1) & 3);
    const int rb2 = eb2 >> 2, sb2 = (eb2 & 3) ^ ((rb2 >> 1) & 3);
    const unsigned short* gB0 = Bt + (size_t)(n0 + rb0)*K + sb0*8;
    const unsigned short* gB1 = Bt + (size_t)(n0 + rb1)*K + sb1*8;
    const unsigned short* gB2 = Bt + (size_t)(n0 + rb2)*K + sb2*8;

#define STAGE192(c, kt) do{ \
    const int ko_ = (kt)*32; \
    gload16(gA0 + ko_, &lA[c][w*512]); \
    gload16(gA1 + ko_, &lA[c][2048 + w*512]); \
    gload16(gB0 + ko_, &lB[c][w*512]); \
    gload16(gB1 + ko_, &lB[c][2048 + w*512]); \
    gload16(gB2 + ko_, &lB[c][4096 + w*512]); \
}while(0)

    f32x4 acc[4][6];
    #pragma unroll
    for (int i=0;i<4;i++)
        #pragma unroll
        for (int j=0;j<6;j++) acc[i][j] = (f32x4){0.f,0.f,0.f,0.f};

    STAGE192(0, 0);
    asm volatile("s_waitcnt vmcnt(0)" ::: "memory");
    __syncthreads();

    int cur = 0;
    for (int kt = 0; kt < nkt; ++kt){
        if (kt + 1 < nkt) STAGE192(cur^1, kt+1);
        bf16x8 af[4], bf[6];
        #pragma unroll
        for (int f=0; f<4; ++f){
            const int rA = wm*64 + f*16 + li;
            af[f] = *(const bf16x8*)&lA[cur][rA*32 + ((ls ^ ((rA>>1)&3))*8)];
        }
        #pragma unroll
        for (int f=0; f<6; ++f){
            const int rB = wn*96 + f*16 + li;
            bf[f] = *(const bf16x8*)&lB[cur][rB*32 + ((ls ^ ((rB>>1)&3))*8)];
        }
        #pragma unroll
        for (int i=0;i<4;i++)
            #pragma unroll
            for (int j=0;j<6;j++)
                acc[i][j] = __builtin_amdgcn_mfma_f32_16x16x32_bf16(af[i], bf[j], acc[i][j], 0, 0, 0);
        __syncthreads();
        cur ^= 1;
    }
#undef STAGE192

    // QKV scatter epilogue
    #pragma unroll
    for (int i=0;i<4;i++){
        #pragma unroll
        for (int j=0;j<6;j++){
            const int row0 = m0 + wm*64 + i*16 + ls*4;
            const int col  = n0 + wn*96 + j*16 + li;
            const int mat = col >> 9, nl = col & 511;
            const int hh = nl >> 5, dd = nl & 31;
            const int bb = row0 / T_, tt0 = row0 - bb*T_;
            if (mat == 2){
                alignas(8) unsigned short p4[4];
                #pragma unroll
                for (int t=0;t<4;t++) p4[t] = f2bf(acc[i][j][t]);
                *(uint2*)(bout + 2*(size_t)(M_*D_)
                          + ((size_t)(bb*H_ + hh)*HD_ + dd)*T_ + tt0) = *(const uint2*)p4;
            } else {
                #pragma unroll
                for (int t=0;t<4;t++){
                    float v = acc[i][j][t];
                    if (mat == 0) v *= QSCALE;
                    bout[(size_t)mat*(M_*D_)
                         + (((size_t)(bb*H_ + hh)*T_ + tt0 + t)*HD_) + dd] = f2bf(v);
                }
            }
        }
    }
}

// ---------------------------------------------------------------------------
// LayerNorm: one wave per row of 512, bf16 in -> bf16 out
// ---------------------------------------------------------------------------
__global__ __launch_bounds__(256) void ln_k(const unsigned short* __restrict__ x,
                                            const float* __restrict__ g,
                                            const float* __restrict__ b,
                                            unsigned short* __restrict__ out)
{
    const int w = threadIdx.x >> 6, lane = threadIdx.x & 63;
    const int row = blockIdx.x*4 + w;
    const unsigned short* xr = x + (size_t)row*D_ + lane*8;
    const uint4 raw = *(const uint4*)xr;
    const unsigned short* rs = (const unsigned short*)&raw;
    float v8[8];
    float s = 0.f, q2 = 0.f;
    #pragma unroll
    for (int i=0;i<8;i++){
        v8[i] = bf2f(rs[i]);
        s  += v8[i];
        q2 += v8[i]*v8[i];
    }
    #pragma unroll
    for (int off=32; off; off>>=1){
        s  += __shfl_xor(s,  off);
        q2 += __shfl_xor(q2, off);
    }
    const float mean = s * (1.f/512.f);
    const float var  = q2 * (1.f/512.f) - mean*mean;
    const float rstd = rsqrtf(var + 1e-6f);
    const float4 gA = *(const float4*)(g + lane*8);
    const float4 gB = *(const float4*)(g + lane*8 + 4);
    const float4 bA = *(const float4*)(b + lane*8);
    const float4 bB = *(const float4*)(b + lane*8 + 4);
    alignas(16) unsigned short o8[8];
    o8[0] = f2bf((v8[0]-mean)*rstd*gA.x + bA.x);
    o8[1] = f2bf((v8[1]-mean)*rstd*gA.y + bA.y);
    o8[2] = f2bf((v8[2]-mean)*rstd*gA.z + bA.z);
    o8[3] = f2bf((v8[3]-mean)*rstd*gA.w + bA.w);
    o8[4] = f2bf((v8[4]-mean)*rstd*gB.x + bB.x);
    o8[5] = f2bf((v8[5]-mean)*rstd*gB.y + bB.y);
    o8[6] = f2bf((v8[6]-mean)*rstd*gB.z + bB.z);
    o8[7] = f2bf((v8[7]-mean)*rstd*gB.w + bB.w);
    *(uint4*)(out + (size_t)row*D_ + lane*8) = *(const uint4*)o8;
}

// ---------------------------------------------------------------------------
// Causal flash attention (R6/R9 proven version). q,k: [bh][T][32] bf16
// (Q pre-scaled by QSCALE), vt: [bh][32][T] bf16. Fixed m=0 softmax, exp2.
// 128 q-rows/block, 32 q-rows/wave via two Q-frags; static named 1-deep
// prefetch regs (rule #20). Boundary chunk peeled. No __syncthreads.
// Grid 1536 x 256 threads, XCD-chunk swizzled.
// ---------------------------------------------------------------------------
__global__ __launch_bounds__(256) void attn_k(const unsigned short* __restrict__ q,
                                              const unsigned short* __restrict__ k,
                                              const unsigned short* __restrict__ vt,
                                              unsigned short* __restrict__ o)
{
    __shared__ unsigned int Pb[4][2*16*18];      // per-wave: A frag @0, B frag @288 (dwords)

    // bijective XCD-chunk swizzle: 1536 = 8 XCDs * 192
    const int orig = blockIdx.x;
    const int wg   = (orig & 7)*192 + (orig >> 3);
    const int bh   = wg / 3;
    const int t0   = (wg - bh*3) * 128;

    const int tid  = threadIdx.x;
    const int lane = tid & 63, w = tid >> 6;
    const int li   = lane & 15, ls = lane >> 4;
    const unsigned short* qb = q  + (size_t)bh*(T_*HD_);
    const unsigned short* kb = k  + (size_t)bh*(T_*HD_);
    const unsigned short* vb = vt + (size_t)bh*(HD_*T_);   // [32][384]

    const int trow0 = t0 + w*32;                 // wave's 32 q-rows
    const bf16x8 qaA = *(const bf16x8*)(qb + (trow0 + li)*HD_ + ls*8);
    const bf16x8 qaB = *(const bf16x8*)(qb + (trow0 + 16 + li)*HD_ + ls*8);
    const int nfull = trow0 >> 5;                // full (unmasked) 32-k chunks

    float lsA = 0.f, lsB = 0.f;
    f32x4 oA0={0.f,0.f,0.f,0.f}, oA1={0.f,0.f,0.f,0.f};
    f32x4 oB0={0.f,0.f,0.f,0.f}, oB1={0.f,0.f,0.f,0.f};
    unsigned int* pwA = Pb[w];
    unsigned int* pwB = Pb[w] + 288;

    bf16x8 kf0 = *(const bf16x8*)(kb + li*HD_ + ls*8);
    bf16x8 kf1 = *(const bf16x8*)(kb + (16 + li)*HD_ + ls*8);
    bf16x8 vf0 = *(const bf16x8*)(vb + li*T_ + ls*8);
    bf16x8 vf1 = *(const bf16x8*)(vb + (16 + li)*T_ + ls*8);

    for (int c = 0; c < nfull; ++c){
        f32x4 sA0={0.f,0.f,0.f,0.f}, sA1={0.f,0.f,0.f,0.f};
        f32x4 sB0={0.f,0.f,0.f,0.f}, sB1={0.f,0.f,0.f,0.f};
        sA0 = __builtin_amdgcn_mfma_f32_16x16x32_bf16(kf0, qaA, sA0, 0, 0, 0);
        sA1 = __builtin_amdgcn_mfma_f32_16x16x32_bf16(kf1, qaA, sA1, 0, 0, 0);
        sB0 = __builtin_amdgcn_mfma_f32_16x16x32_bf16(kf0, qaB, sB0, 0, 0, 0);
        sB1 = __builtin_amdgcn_mfma_f32_16x16x32_bf16(kf1, qaB, sB1, 0, 0, 0);
        kf0 = *(const bf16x8*)(kb + ((c+1)*32 + li)*HD_ + ls*8);
        kf1 = *(const bf16x8*)(kb + ((c+1)*32 + 16 + li)*HD_ + ls*8);

        float pA0[4], pA1[4], pB0[4], pB1[4];
        #pragma unroll
        for (int j=0;j<4;j++){
            pA0[j] = exp2f(sA0[j]); pA1[j] = exp2f(sA1[j]);
            pB0[j] = exp2f(sB0[j]); pB1[j] = exp2f(sB1[j]);
        }
        lsA += pA0[0]+pA0[1]+pA0[2]+pA0[3]+pA1[0]+pA1[1]+pA1[2]+pA1[3];
        lsB += pB0[0]+pB0[1]+pB0[2]+pB0[3]+pB1[0]+pB1[1]+pB1[2]+pB1[3];

        const uint2 wA0 = { cvtpk(pA0[0], pA0[1]), cvtpk(pA0[2], pA0[3]) };
        const uint2 wA1 = { cvtpk(pA1[0], pA1[1]), cvtpk(pA1[2], pA1[3]) };
        const uint2 wB0 = { cvtpk(pB0[0], pB0[1]), cvtpk(pB0[2], pB0[3]) };
        const uint2 wB1 = { cvtpk(pB1[0], pB1[1]), cvtpk(pB1[2], pB1[3]) };
        *(uint2*)&pwA[li*18 + ls*2]     = wA0;
        *(uint2*)&pwA[li*18 + 8 + ls*2] = wA1;
        *(uint2*)&pwB[li*18 + ls*2]     = wB0;
        *(uint2*)&pwB[li*18 + 8 + ls*2] = wB1;
        asm volatile("s_waitcnt lgkmcnt(0)" ::: "memory");
        const bf16x8 paA = *(const bf16x8*)&pwA[li*18 + ls*4];
        const bf16x8 paB = *(const bf16x8*)&pwB[li*18 + ls*4];

        oA0 = __builtin_amdgcn_mfma_f32_16x16x32_bf16(paA, vf0, oA0, 0, 0, 0);
        oA1 = __builtin_amdgcn_mfma_f32_16x16x32_bf16(paA, vf1, oA1, 0, 0, 0);
        oB0 = __builtin_amdgcn_mfma_f32_16x16x32_bf16(paB, vf0, oB0, 0, 0, 0);
        oB1 = __builtin_amdgcn_mfma_f32_16x16x32_bf16(paB, vf1, oB1, 0, 0, 0);
        vf0 = *(const bf16x8*)(vb + li*T_ + (c+1)*32 + ls*8);
        vf1 = *(const bf16x8*)(vb + (16 + li)*T_ + (c+1)*32 + ls*8);
    }

    // ---- boundary chunk c = nfull (k base = trow0), causal-masked ----
    {
        f32x4 sA0={0.f,0.f,0.f,0.f}, sB0={0.f,0.f,0.f,0.f}, sB1={0.f,0.f,0.f,0.f};
        sA0 = __builtin_amdgcn_mfma_f32_16x16x32_bf16(kf0, qaA, sA0, 0, 0, 0);
        sB0 = __builtin_amdgcn_mfma_f32_16x16x32_bf16(kf0, qaB, sB0, 0, 0, 0);
        sB1 = __builtin_amdgcn_mfma_f32_16x16x32_bf16(kf1, qaB, sB1, 0, 0, 0);

        const int qA = li, qB = 16 + li;
        float pA0[4], pB0[4], pB1[4];
        #pragma unroll
        for (int j=0;j<4;j++){
            const int k0 = ls*4 + j;
            pA0[j] = (k0 <= qA)      ? exp2f(sA0[j]) : 0.f;
            pB0[j] = exp2f(sB0[j]);
            pB1[j] = (k0 + 16 <= qB) ? exp2f(sB1[j]) : 0.f;
        }
        lsA += pA0[0]+pA0[1]+pA0[2]+pA0[3];
        lsB += pB0[0]+pB0[1]+pB0[2]+pB0[3]+pB1[0]+pB1[1]+pB1[2]+pB1[3];

        const uint2 wA0 = { cvtpk(pA0[0], pA0[1]), cvtpk(pA0[2], pA0[3]) };
        const uint2 wB0 = { cvtpk(pB0[0], pB0[1]), cvtpk(pB0[2], pB0[3]) };
        const uint2 wB1 = { cvtpk(pB1[0], pB1[1]), cvtpk(pB1[2], pB1[3]) };
        const uint2 zz  = { 0u, 0u };
        *(uint2*)&pwA[li*18 + ls*2]     = wA0;
        *(uint2*)&pwA[li*18 + 8 + ls*2] = zz;
        *(uint2*)&pwB[li*18 + ls*2]     = wB0;
        *(uint2*)&pwB[li*18 + 8 + ls*2] = wB1;
        asm volatile("s_waitcnt lgkmcnt(0)" ::: "memory");
        const bf16x8 paA = *(const bf16x8*)&pwA[li*18 + ls*4];
        const bf16x8 paB = *(const bf16x8*)&pwB[li*18 + ls*4];

        oA0 = __builtin_amdgcn_mfma_f32_16x16x32_bf16(paA, vf0, oA0, 0, 0, 0);
        oA1 = __builtin_amdgcn_mfma_f32_16x16x32_bf16(paA, vf1, oA1, 0, 0, 0);
        oB0 = __builtin_amdgcn_mfma_f32_16x16x32_bf16(paB, vf0, oB0, 0, 0, 0);
        oB1 = __builtin_amdgcn_mfma_f32_16x16x32_bf16(paB, vf1, oB1, 0, 0, 0);
    }

    lsA += __shfl_xor(lsA, 16);  lsA += __shfl_xor(lsA, 32);
    lsB += __shfl_xor(lsB, 16);  lsB += __shfl_xor(lsB, 32);

    const int bb = bh >> 4, hh = bh & 15;
    #pragma unroll
    for (int j=0;j<4;j++){
        const float rsA = __shfl(lsA, ls*4 + j);
        const float rsB = __shfl(lsB, ls*4 + j);
        const float iA = 1.f / rsA, iB = 1.f / rsB;
        const int tgA = trow0 + ls*4 + j;
        const int tgB = tgA + 16;
        o[(size_t)(bb*T_ + tgA)*D_ + hh*HD_ + li]      = f2bf(oA0[j]*iA);
        o[(size_t)(bb*T_ + tgA)*D_ + hh*HD_ + 16 + li] = f2bf(oA1[j]*iA);
        o[(size_t)(bb*T_ + tgB)*D_ + hh*HD_ + li]      = f2bf(oB0[j]*iB);
        o[(size_t)(bb*T_ + tgB)*D_ + hh*HD_ + 16 + li] = f2bf(oB1[j]*iB);
    }
}

// ---------------------------------------------------------------------------
// Coalesced tiled transpose packs (f32 -> bf16)
// ---------------------------------------------------------------------------
__global__ __launch_bounds__(256) void packT_k(const float* __restrict__ src,
                                               unsigned short* __restrict__ dst,
                                               int R, int C)
{
    __shared__ unsigned short tile[64][72];
    const int z  = blockIdx.z;
    const float* s = src + (size_t)z*R*C;
    unsigned short* d = dst + (size_t)z*R*C;
    const int c0 = blockIdx.x*64, r0 = blockIdx.y*64;

    for (int it = threadIdx.x; it < 1024; it += 256){
        const int rr  = it >> 4;
        const int cc4 = (it & 15) << 2;
        const float4 v = *(const float4*)(s + (size_t)(r0+rr)*C + c0 + cc4);
        tile[cc4  ][rr] = f2bf(v.x);
        tile[cc4+1][rr] = f2bf(v.y);
        tile[cc4+2][rr] = f2bf(v.z);
        tile[cc4+3][rr] = f2bf(v.w);
    }
    __syncthreads();
    for (int it = threadIdx.x; it < 512; it += 256){
        const int cc = it >> 3;
        const int ch = (it & 7) << 3;
        *(uint4*)(d + (size_t)(c0+cc)*R + r0 + ch) = *(const uint4*)&tile[cc][ch];
    }
}

__global__ __launch_bounds__(256) void pack_qkv_k(const float* __restrict__ Wq,
                                                  const float* __restrict__ Wk,
                                                  const float* __restrict__ Wv,
                                                  unsigned short* __restrict__ dst)
{
    __shared__ unsigned short tile[32][136];
    const int kc  = blockIdx.x;
    const int mat = blockIdx.y >> 4;
    const int h   = blockIdx.y & 15;
    const int l   = blockIdx.z;
    const float* src = ((mat==0) ? Wq : (mat==1) ? Wk : Wv)
                     + ((size_t)(l*H_ + h)*D_ + kc*128)*HD_;

    for (int it = threadIdx.x; it < 1024; it += 256){
        const int rr  = it >> 3;
        const int dd4 = (it & 7) << 2;
        const float4 v = *(const float4*)(src + (size_t)rr*HD_ + dd4);
        tile[dd4  ][rr] = f2bf(v.x);
        tile[dd4+1][rr] = f2bf(v.y);
        tile[dd4+2][rr] = f2bf(v.z);
        tile[dd4+3][rr] = f2bf(v.w);
    }
    __syncthreads();
    unsigned short* dp = dst + (size_t)l*786432 + (size_t)mat*262144 + kc*128;
    for (int it = threadIdx.x; it < 512; it += 256){
        const int dd = it >> 4;
        const int ch = (it & 15) << 3;
        *(uint4*)(dp + (size_t)(h*32 + dd)*512 + ch) = *(const uint4*)&tile[dd][ch];
    }
}

__global__ void cast4_k(const float* __restrict__ src, unsigned short* __restrict__ dst, int total4)
{
    const int i = blockIdx.x*256 + threadIdx.x;
    if (i >= total4) return;
    const float4 vv = ((const float4*)src)[i];
    alignas(8) unsigned short t[4] = { f2bf(vv.x), f2bf(vv.y), f2bf(vv.z), f2bf(vv.w) };
    *(uint2*)(dst + (size_t)i*4) = *(const uint2*)t;
}

__global__ __launch_bounds__(256) void loss2_k(const float* __restrict__ part,
                                               float* __restrict__ out)
{
    float s = 0.f;
    for (int i = threadIdx.x; i < 192; i += 256) s += part[i];
    #pragma unroll
    for (int off=32; off; off>>=1) s += __shfl_xor(s, off);
    __shared__ float ws4[4];
    if ((threadIdx.x & 63) == 0) ws4[threadIdx.x >> 6] = s;
    __syncthreads();
    if (threadIdx.x == 0) out[0] = (ws4[0]+ws4[1]+ws4[2]+ws4[3]) * (1.f/(float)(M_*CF_));
}

// ---------------------------------------------------------------------------
// Host
// ---------------------------------------------------------------------------
static constexpr size_t X_OFF     = 0;            // bf16 x       12,582,912 B (region reserved 25 MB)
static constexpr size_t H_OFF     = 25165824;     // bf16 h/xb    12,582,912 B
static constexpr size_t O_OFF     = 37748736;     // bf16 o/u/idx 12,582,912 B
static constexpr size_t QKV_OFF   = 50331648;     // bf16 q,k,vt  37,748,736 B
static constexpr size_t WQKV_OFF  = 88080384;     // bf16         25,165,824 B
static constexpr size_t WPROJ_OFF = 113246208;    // bf16          8,388,608 B
static constexpr size_t W1_OFF    = 121634816;    // bf16          8,388,608 B
static constexpr size_t W2_OFF    = 130023424;    // bf16          8,388,608 B
static constexpr size_t WEMB_OFF  = 138412032;    // bf16            131,072 B
static constexpr size_t WFIN_OFF  = 138543104;    // bf16            131,072 B
static constexpr size_t PART_OFF  = 138674176;    // f32               4,096 B

extern "C" void kernel_launch(void* const* d_in, const int* in_sizes, int n_in,
                              void* d_out, int out_size, void* d_ws, size_t ws_size,
                              hipStream_t stream)
{
    const float* index   = (const float*)d_in[0];
    const float* targets = (const float*)d_in[1];
    const float* W_embed = (const float*)d_in[2];
    const float* b_embed = (const float*)d_in[3];
    const float* pe      = (const float*)d_in[4];
    const float* lpe     = (const float*)d_in[5];
    const float* Wq      = (const float*)d_in[6];
    const float* Wk      = (const float*)d_in[7];
    const float* Wv      = (const float*)d_in[8];
    const float* Wproj   = (const float*)d_in[9];
    const float* bproj   = (const float*)d_in[10];
    const float* ln1g    = (const float*)d_in[11];
    const float* ln1b    = (const float*)d_in[12];
    const float* ln2g    = (const float*)d_in[13];
    const float* ln2b    = (const float*)d_in[14];
    const float* W1      = (const float*)d_in[15];
    const float* b1      = (const float*)d_in[16];
    const float* W2      = (const float*)d_in[17];
    const float* b2      = (const float*)d_in[18];
    const float* Wfin    = (const float*)d_in[19];
    const float* bfin    = (const float*)d_in[20];

    char* ws = (char*)d_ws;
    unsigned short* xb    = (unsigned short*)(ws + X_OFF);
    unsigned short* hbuf  = (unsigned short*)(ws + H_OFF);
    unsigned short* obuf  = (unsigned short*)(ws + O_OFF);
    unsigned short* qkv   = (unsigned short*)(ws + QKV_OFF);
    unsigned short* wqkvp = (unsigned short*)(ws + WQKV_OFF);
    unsigned short* wprojp= (unsigned short*)(ws + WPROJ_OFF);
    unsigned short* w1p   = (unsigned short*)(ws + W1_OFF);
    unsigned short* w2p   = (unsigned short*)(ws + W2_OFF);
    unsigned short* wembp = (unsigned short*)(ws + WEMB_OFF);
    unsigned short* wfinp = (unsigned short*)(ws + WFIN_OFF);
    float*          part  = (float*)(ws + PART_OFF);
    float*          logits= (float*)d_out;

    // pack weights to bf16 B^T layouts (coalesced LDS-transpose)
    pack_qkv_k<<<dim3(4,48,16), 256, 0, stream>>>(Wq, Wk, Wv, wqkvp);
    packT_k<<<dim3(8,8,16), 256, 0, stream>>>(Wproj, wprojp, 512, 512);
    packT_k<<<dim3(8,8,16), 256, 0, stream>>>(W1,    w1p,    512, 512);
    packT_k<<<dim3(8,8,16), 256, 0, stream>>>(W2,    w2p,    512, 512);
    packT_k<<<dim3(8,2,1),  256, 0, stream>>>(W_embed, wembp, 128, 512);
    packT_k<<<dim3(2,8,1),  256, 0, stream>>>(Wfin,    wfinp, 512, 128);

    // embed: x = bf16(index) @ Wemb^T + b + pe + lpe   (x in bf16)
    cast4_k<<<1536, 256, 0, stream>>>(index, obuf, 393216);
    gemm_k<0><<<dim3(192,4), 256, 0, stream>>>(obuf, wembp, b_embed, pe, lpe, nullptr, xb, nullptr, 128);

    for (int l = 0; l < L_; ++l){
        ln_k<<<3072, 256, 0, stream>>>(xb, ln1g + l*512, ln1b + l*512, hbuf);
        gemm192_k<<<dim3(96,8), 256, 0, stream>>>(hbuf, wqkvp + (size_t)l*786432, qkv, 512);
        attn_k<<<1536, 256, 0, stream>>>(qkv, qkv + 6291456, qkv + 2*6291456, obuf);
        gemm_k<2><<<dim3(192,4), 256, 0, stream>>>(obuf, wprojp + (size_t)l*262144,
                                                   bproj + l*512, nullptr, nullptr, nullptr, xb, nullptr, 512);
        ln_k<<<3072, 256, 0, stream>>>(xb, ln2g + l*512, ln2b + l*512, hbuf);
        gemm_k<3><<<dim3(192,4), 256, 0, stream>>>(hbuf, w1p + (size_t)l*262144,
                                                   b1 + l*512, nullptr, nullptr, nullptr, obuf, nullptr, 512);
        gemm_k<2><<<dim3(192,4), 256, 0, stream>>>(obuf, w2p + (size_t)l*262144,
                                                   b2 + l*512, nullptr, nullptr, nullptr, xb, nullptr, 512);
    }

    // final: logits = x @ Wfin^T + b_final ; loss fused into epilogue partials
    gemm_k<4><<<dim3(192,1), 256, 0, stream>>>(xb, wfinp, bfin, targets, nullptr, logits, nullptr, part, 512);
    loss2_k<<<1, 256, 0, stream>>>(part, logits + 1572864);
}